// Round 2
// baseline (157.963 us; speedup 1.0000x reference)
//
#include <hip/hip_runtime.h>

#define BB 4
#define NN 256
#define DMM 128
#define DEE 8
#define HH 8
#define DD 16
#define LAYERS 2
#define SCALE 0.25f
#define PS 260   // padded LDS stride (floats): float4-aligned (260%4==0), breaks 256-stride bank patterns

struct Params {
  const float *nodes, *edges, *adjacency;
  const float *Wq, *bq, *Wk, *bk, *Wv, *bv, *We, *be, *Wres, *bres, *Wgate, *lng, *lnb;
  const float *src;                 // layer input: nodes (l=0) or x (l=1)
  float *x, *q, *k, *v, *res;       // fp32 workspace
  float *out;                       // final output (fp32)
  int layer;
};

// q,k,v,res = src @ W* + b*   (4 rows per block; wave m handles one matrix)
__global__ __launch_bounds__(256) void k_proj(Params P){
  const int t = threadIdx.x;
  const int m = t >> 6;       // 0=q 1=k 2=v 3=res (wave-uniform)
  const int cp = t & 63;      // column pair
  const int row0 = blockIdx.x * 4;
  const int l = P.layer;
  const float *W, *bia; float* dst;
  if (m==0){ W = P.Wq + l*DMM*DMM; bia = P.bq + l*DMM; dst = P.q; }
  else if (m==1){ W = P.Wk + l*DMM*DMM; bia = P.bk + l*DMM; dst = P.k; }
  else if (m==2){ W = P.Wv + l*DMM*DMM; bia = P.bv + l*DMM; dst = P.v; }
  else { W = P.Wres + l*DMM*DMM; bia = P.bres + l*DMM; dst = P.res; }
  const float2 bv2 = *(const float2*)(bia + 2*cp);
  float acc0[4] = {bv2.x,bv2.x,bv2.x,bv2.x};
  float acc1[4] = {bv2.y,bv2.y,bv2.y,bv2.y};
  const float2* W2 = (const float2*)W;      // column pair cp of row kk at kk*64+cp
  const float* xr = P.src + row0*DMM;       // wave-uniform -> scalar loads
  #pragma unroll 8
  for (int kk=0; kk<DMM; kk++){
    float2 w = W2[kk*64+cp];
    #pragma unroll
    for (int r=0;r<4;r++){
      float xv = xr[r*DMM+kk];
      acc0[r] += xv*w.x; acc1[r] += xv*w.y;
    }
  }
  #pragma unroll
  for (int r=0;r<4;r++){
    *(float2*)(dst + (row0+r)*DMM + 2*cp) = make_float2(acc0[r], acc1[r]);
  }
}

// fused attention + gated residual + layernorm + relu; one block per (b,i)
// NOTE: the reference's mean-shift (means[i] from bh=0) cancels exactly in
// _adj_softmax (exp(-m) factors out of numerator and denominator; s==0 rows
// behave identically), so no shift is applied here. |sim| <~ 1, exp is safe.
__global__ __launch_bounds__(256) void k_attn(Params P){
  const int t = threadIdx.x;
  const int b = blockIdx.x >> 8;
  const int i = blockIdx.x & 255;
  const int l = P.layer;

  __shared__ float qs[128];
  __shared__ float qwe_s[64];     // [h][c] = sum_d q_hd * We[c,hd]
  __shared__ float qbe_s[8];      // [h]    = sum_d q_hd * be[hd]
  __shared__ float es[8*PS];      // edges row transposed [c][j]
  __shared__ float ps[8*PS];      // p [h][j]
  __shared__ float red_s[32];     // [wave][h] partial p-sums
  __shared__ float ssum_s[8];
  __shared__ float g_s[64];       // [h][c] = sum_j p*edges
  __shared__ float res_s[128];
  __shared__ float red_a[2], red_b[2], red_c[2];

  if (t < 128) qs[t] = P.q[(b*NN+i)*DMM + t];
  __syncthreads();
  if (t < 64){
    const int h = t>>3, c = t&7;
    const float* Wer = P.We + l*DEE*DMM + c*DMM + h*DD;
    float a = 0.f;
    #pragma unroll
    for (int d=0; d<DD; d++) a += qs[h*DD+d]*Wer[d];
    qwe_s[t] = a;
    if (c==0){
      const float* ber = P.be + l*DMM + h*DD;
      float a2 = 0.f;
      #pragma unroll
      for (int d=0; d<DD; d++) a2 += qs[h*DD+d]*ber[d];
      qbe_s[h] = a2;
    }
  }
  __syncthreads();

  // ---- phase 1: thread j computes p (unnormalized attn) for all 8 heads ----
  {
    const int j = t;
    const float4* er4 = (const float4*)(P.edges + ((size_t)(b*NN+i)*NN + j)*DEE);
    float4 e0 = er4[0], e1 = er4[1];
    float ec[8] = {e0.x,e0.y,e0.z,e0.w, e1.x,e1.y,e1.z,e1.w};
    #pragma unroll
    for (int c=0;c<8;c++) es[c*PS+j] = ec[c];
    const float adj = P.adjacency[(size_t)(b*NN+i)*NN + j];
    const float4* kr = (const float4*)(P.k + (b*NN+j)*DMM);
    const float* qg = P.q + (b*NN+i)*DMM;    // uniform address -> scalar loads
    float preg[8];
    #pragma unroll
    for (int h=0; h<HH; h++){
      float4 k0 = kr[h*4+0], k1 = kr[h*4+1], k2 = kr[h*4+2], k3 = kr[h*4+3];
      const float* qh = qg + h*DD;
      float sim = qbe_s[h];
      sim += qh[0]*k0.x + qh[1]*k0.y + qh[2]*k0.z + qh[3]*k0.w;
      sim += qh[4]*k1.x + qh[5]*k1.y + qh[6]*k1.z + qh[7]*k1.w;
      sim += qh[8]*k2.x + qh[9]*k2.y + qh[10]*k2.z + qh[11]*k2.w;
      sim += qh[12]*k3.x + qh[13]*k3.y + qh[14]*k3.z + qh[15]*k3.w;
      const float4* qw4 = (const float4*)(qwe_s + h*8);
      float4 wA = qw4[0], wB = qw4[1];
      sim += ec[0]*wA.x + ec[1]*wA.y + ec[2]*wA.z + ec[3]*wA.w;
      sim += ec[4]*wB.x + ec[5]*wB.y + ec[6]*wB.z + ec[7]*wB.w;
      sim *= SCALE;
      float p = __expf(sim) * adj;
      preg[h] = p;
      ps[h*PS+j] = p;
    }
    #pragma unroll
    for (int h=0; h<HH; h++){
      float v = preg[h];
      #pragma unroll
      for (int off=32; off; off>>=1) v += __shfl_xor(v, off, 64);
      if ((t&63)==0) red_s[(t>>6)*8 + h] = v;
    }
  }
  __syncthreads();

  // ---- phase 2: pv (t<128), g=sum_j p*edges (128<=t<192), res+ssum (t>=192) ----
  float pv = 0.f;
  if (t < 128){
    const int h = t>>4, d = t&15;
    const float* vcol = P.v + b*NN*DMM + h*DD + d;
    const float4* pr = (const float4*)(ps + h*PS);
    #pragma unroll 4
    for (int jq=0; jq<64; jq++){
      float4 pp = pr[jq];
      const float* vv = vcol + jq*4*DMM;
      pv += pp.x*vv[0] + pp.y*vv[DMM] + pp.z*vv[2*DMM] + pp.w*vv[3*DMM];
    }
  } else if (t < 192){
    const int h = (t-128)>>3, c = (t-128)&7;
    const float4* pr = (const float4*)(ps + h*PS);
    const float4* er = (const float4*)(es + c*PS);
    float g = 0.f;
    #pragma unroll 4
    for (int jq=0; jq<64; jq++){
      float4 pp = pr[jq], ee = er[jq];
      g += pp.x*ee.x + pp.y*ee.y + pp.z*ee.z + pp.w*ee.w;
    }
    g_s[h*8+c] = g;
  } else {
    const int u = t - 192;
    const float2 rv = *(const float2*)(P.res + (b*NN+i)*DMM + 2*u);
    res_s[2*u] = rv.x; res_s[2*u+1] = rv.y;
    if (t >= 248){
      const int h = t - 248;
      ssum_s[h] = red_s[h] + red_s[8+h] + red_s[16+h] + red_s[24+h];
    }
  }
  __syncthreads();

  // ---- phase 3: assemble out, gate reduction ----
  float o = 0.f, rr = 0.f;
  if (t < 128){
    const int h = t>>4;
    const float* Wec = P.We + l*DEE*DMM + t;   // column hd=t, stride DMM over c
    float eacc = 0.f;
    #pragma unroll
    for (int c=0;c<8;c++) eacc += Wec[c*DMM] * g_s[h*8+c];
    const float ssum = ssum_s[h];
    const float denom = (ssum==0.f) ? 1.f : ssum;
    const float bev = P.be[l*DMM + t];
    o = (pv + eacc + ssum*bev) / denom;
    rr = res_s[t];
    const float* Wg = P.Wgate + l*3*DMM;
    float contrib = o*Wg[t] + rr*Wg[DMM+t] + (o-rr)*Wg[2*DMM+t];
    #pragma unroll
    for (int off=32; off; off>>=1) contrib += __shfl_xor(contrib, off, 64);
    if ((t&63)==0) red_a[t>>6] = contrib;
  }
  __syncthreads();

  float y = 0.f;
  if (t < 128){
    const float gs = red_a[0] + red_a[1];
    const float gate = 1.f/(1.f + __expf(-gs));
    y = o*gate + rr*(1.f-gate);
    float s1 = y, s2 = y*y;
    #pragma unroll
    for (int off=32; off; off>>=1){ s1 += __shfl_xor(s1, off, 64); s2 += __shfl_xor(s2, off, 64); }
    if ((t&63)==0){ red_b[t>>6] = s1; red_c[t>>6] = s2; }
  }
  __syncthreads();

  if (t < 128){
    const float mu  = (red_b[0]+red_b[1]) * (1.f/128.f);
    const float var = (red_c[0]+red_c[1]) * (1.f/128.f) - mu*mu;
    const float inv = rsqrtf(var + 1e-5f);
    float yn = (y - mu)*inv*P.lng[l*DMM+t] + P.lnb[l*DMM+t];
    yn = fmaxf(yn, 0.f);
    if (l == LAYERS-1) P.out[(b*NN+i)*DMM + t] = yn;
    else               P.x  [(b*NN+i)*DMM + t] = yn;
  }
}

extern "C" void kernel_launch(void* const* d_in, const int* in_sizes, int n_in,
                              void* d_out, int out_size, void* d_ws, size_t ws_size,
                              hipStream_t stream) {
  Params P;
  P.nodes     = (const float*)d_in[0];
  P.edges     = (const float*)d_in[1];
  P.adjacency = (const float*)d_in[2];
  P.Wq   = (const float*)d_in[3];  P.bq   = (const float*)d_in[4];
  P.Wk   = (const float*)d_in[5];  P.bk   = (const float*)d_in[6];
  P.Wv   = (const float*)d_in[7];  P.bv   = (const float*)d_in[8];
  P.We   = (const float*)d_in[9];  P.be   = (const float*)d_in[10];
  P.Wres = (const float*)d_in[11]; P.bres = (const float*)d_in[12];
  P.Wgate= (const float*)d_in[13];
  P.lng  = (const float*)d_in[14]; P.lnb  = (const float*)d_in[15];

  float* f = (float*)d_ws;
  const int S = BB*NN*DMM;   // 131072
  P.x = f; P.q = f + S; P.k = f + 2*S; P.v = f + 3*S; P.res = f + 4*S;
  P.out = (float*)d_out;

  for (int l = 0; l < LAYERS; l++){
    P.layer = l;
    P.src = (l == 0) ? P.nodes : P.x;
    k_proj <<<256,  256, 0, stream>>>(P);
    k_attn <<<BB*NN,256, 0, stream>>>(P);
  }
}